// Round 10
// baseline (201.203 us; speedup 1.0000x reference)
//
#include <hip/hip_runtime.h>

#define NBATCH 8
#define RANGE_BIG  13312   // 13312*3*4 = 159744 B dynamic LDS (1 block/CU)
#define MAXSEG 4

// Packed triples (align 4) -> global_load_dwordx3.
struct I3 { int a, b, c; };
struct P3 { float x, y, z; };

// ---------------------------------------------------------------------------
// Cotangent weights per the reference (Heron, EPS guard, A==0 -> 0).
// ---------------------------------------------------------------------------
__device__ __forceinline__ void cot_weights(
    const P3& p0, const P3& p1, const P3& p2,
    float& w0, float& w1, float& w2)
{
    const float EPSf = 1e-10f;
    float dx, dy, dz;
    dx = p1.x - p2.x; dy = p1.y - p2.y; dz = p1.z - p2.z;
    float l1 = sqrtf(dx * dx + dy * dy + dz * dz);   // |v2 - v3|
    dx = p2.x - p0.x; dy = p2.y - p0.y; dz = p2.z - p0.z;
    float l2 = sqrtf(dx * dx + dy * dy + dz * dz);   // |v3 - v1|
    dx = p0.x - p1.x; dy = p0.y - p1.y; dz = p0.z - p1.z;
    float l3 = sqrtf(dx * dx + dy * dy + dz * dz);   // |v1 - v2|

    float sp = (l1 + l2 + l3) * 0.5f;
    float inside = sp * (sp - l1) * (sp - l2) * (sp - l3);
    inside = fmaxf(inside, 0.0f);
    float A = 2.0f * sqrtf(inside);
    float denom = A + EPSf;

    float l1s = l1 * l1, l2s = l2 * l2, l3s = l3 * l3;
    w0 = (l2s + l3s - l1s) / denom * 0.25f;
    w1 = (l1s + l3s - l2s) / denom * 0.25f;
    w2 = (l1s + l2s - l3s) / denom * 0.25f;
    if (A == 0.0f) { w0 = 0.0f; w1 = 0.0f; w2 = 0.0f; }
}

// ---------------------------------------------------------------------------
// Phase A: one thread per face. Compute weights ONCE, store the 9
// degree-folded per-corner contribution floats. cbuf layout: [b*Fc+f][9].
// ---------------------------------------------------------------------------
__global__ void __launch_bounds__(256) cot_prep(
    const float* __restrict__ V, const int* __restrict__ F,
    float* __restrict__ cbuf, int N, int Fc)
{
    int idx = blockIdx.x * blockDim.x + threadIdx.x;
    int total = NBATCH * Fc;
    if (idx >= total) return;

    int b = idx / Fc;
    I3 ix = *reinterpret_cast<const I3*>(F + (size_t)idx * 3);
    const float* Vb = V + (size_t)b * N * 3;
    P3 p0 = *reinterpret_cast<const P3*>(Vb + (size_t)ix.a * 3);
    P3 p1 = *reinterpret_cast<const P3*>(Vb + (size_t)ix.b * 3);
    P3 p2 = *reinterpret_cast<const P3*>(Vb + (size_t)ix.c * 3);

    float w0, w1, w2;
    cot_weights(p0, p1, p2, w0, w1, w2);

    float* c = cbuf + (size_t)idx * 9;
    c[0] = w1 * (p2.x - p0.x) + w2 * (p1.x - p0.x);
    c[1] = w1 * (p2.y - p0.y) + w2 * (p1.y - p0.y);
    c[2] = w1 * (p2.z - p0.z) + w2 * (p1.z - p0.z);
    c[3] = w0 * (p2.x - p1.x) + w2 * (p0.x - p1.x);
    c[4] = w0 * (p2.y - p1.y) + w2 * (p0.y - p1.y);
    c[5] = w0 * (p2.z - p1.z) + w2 * (p0.z - p1.z);
    c[6] = w0 * (p1.x - p2.x) + w1 * (p0.x - p2.x);
    c[7] = w0 * (p1.y - p2.y) + w1 * (p0.y - p2.y);
    c[8] = w0 * (p1.z - p2.z) + w1 * (p0.z - p2.z);
}

// ---------------------------------------------------------------------------
// Phase B: scan F per (batch, range, segment); per corner-hit load 3 floats
// from cbuf and ds_add into the LDS tile. No geometry in the loop.
// ---------------------------------------------------------------------------
__global__ void __launch_bounds__(1024, 1) cot_scatter_big(
    const int*   __restrict__ F, const float* __restrict__ cbuf,
    float*       __restrict__ part, int N, int Fc, int BN3, int nseg)
{
    extern __shared__ float lacc[];
    int nr = (N + RANGE_BIG - 1) / RANGE_BIG;

    int b = blockIdx.x % NBATCH;
    int t = blockIdx.x / NBATCH;
    int r = t / nseg;
    int s = t % nseg;
    if (r >= nr) return;

    int lo = r * RANGE_BIG;
    int hi = min(lo + RANGE_BIG, N);
    unsigned rlen = (unsigned)(hi - lo);
    int len3 = (hi - lo) * 3;

    for (int i = threadIdx.x; i < len3; i += 1024) lacc[i] = 0.0f;
    __syncthreads();

    int fps = (Fc + nseg - 1) / nseg;
    int f0 = s * fps;
    int f1 = min(f0 + fps, Fc);

    const int*   Fb = F + (size_t)b * Fc * 3;
    const float* Cb = cbuf + (size_t)b * Fc * 9;

    for (int f = f0 + (int)threadIdx.x; f < f1; f += 1024) {
        I3 ix = *reinterpret_cast<const I3*>(Fb + (size_t)f * 3);   // dwordx3
        unsigned u0 = (unsigned)(ix.a - lo);
        unsigned u1 = (unsigned)(ix.b - lo);
        unsigned u2 = (unsigned)(ix.c - lo);
        bool in0 = u0 < rlen, in1 = u1 < rlen, in2 = u2 < rlen;
        if (!(in0 || in1 || in2)) continue;

        const float* c = Cb + (size_t)f * 9;
        if (in0) {
            atomicAdd(&lacc[u0 * 3 + 0], c[0]);
            atomicAdd(&lacc[u0 * 3 + 1], c[1]);
            atomicAdd(&lacc[u0 * 3 + 2], c[2]);
        }
        if (in1) {
            atomicAdd(&lacc[u1 * 3 + 0], c[3]);
            atomicAdd(&lacc[u1 * 3 + 1], c[4]);
            atomicAdd(&lacc[u1 * 3 + 2], c[5]);
        }
        if (in2) {
            atomicAdd(&lacc[u2 * 3 + 0], c[6]);
            atomicAdd(&lacc[u2 * 3 + 1], c[7]);
            atomicAdd(&lacc[u2 * 3 + 2], c[8]);
        }
    }
    __syncthreads();

    float* dst = part + (size_t)s * BN3 + ((size_t)b * N + lo) * 3;
    for (int i = threadIdx.x; i < len3; i += 1024) dst[i] = lacc[i];
}

// ---------------------------------------------------------------------------
// Merge nseg partials -> out (float4 fast path).
// ---------------------------------------------------------------------------
__global__ void __launch_bounds__(256) cot_merge4(
    const float* __restrict__ part, float* __restrict__ out, int BN3, int nseg)
{
    int i = blockIdx.x * blockDim.x + threadIdx.x;
    int n4 = BN3 >> 2;
    if (i >= n4) return;
    float4 a = ((const float4*)part)[i];
    for (int s = 1; s < nseg; ++s) {
        float4 p = ((const float4*)(part + (size_t)s * BN3))[i];
        a.x += p.x; a.y += p.y; a.z += p.z; a.w += p.w;
    }
    ((float4*)out)[i] = a;
}

__global__ void __launch_bounds__(256) cot_merge1(
    const float* __restrict__ part, float* __restrict__ out, int BN3, int nseg)
{
    int i = blockIdx.x * blockDim.x + threadIdx.x;
    if (i >= BN3) return;
    float v = part[i];
    for (int s = 1; s < nseg; ++s) v += part[(size_t)s * BN3 + i];
    out[i] = v;
}

// ---------------------------------------------------------------------------
// Fallback 1 (round-9 measured path): fused gather with in-loop geometry.
// ---------------------------------------------------------------------------
__global__ void __launch_bounds__(1024, 1) cot_gather_big(
    const float* __restrict__ V, const int* __restrict__ F,
    float* __restrict__ part, int N, int Fc, int BN3, int nseg)
{
    extern __shared__ float lacc[];
    int nr = (N + RANGE_BIG - 1) / RANGE_BIG;

    int b = blockIdx.x % NBATCH;
    int t = blockIdx.x / NBATCH;
    int r = t / nseg;
    int s = t % nseg;
    if (r >= nr) return;

    int lo = r * RANGE_BIG;
    int hi = min(lo + RANGE_BIG, N);
    unsigned rlen = (unsigned)(hi - lo);
    int len3 = (hi - lo) * 3;

    for (int i = threadIdx.x; i < len3; i += 1024) lacc[i] = 0.0f;
    __syncthreads();

    int fps = (Fc + nseg - 1) / nseg;
    int f0 = s * fps;
    int f1 = min(f0 + fps, Fc);

    const int*   Fb = F + (size_t)b * Fc * 3;
    const float* Vb = V + (size_t)b * N * 3;

    for (int f = f0 + (int)threadIdx.x; f < f1; f += 1024) {
        I3 ix = *reinterpret_cast<const I3*>(Fb + (size_t)f * 3);
        unsigned u0 = (unsigned)(ix.a - lo);
        unsigned u1 = (unsigned)(ix.b - lo);
        unsigned u2 = (unsigned)(ix.c - lo);
        bool in0 = u0 < rlen, in1 = u1 < rlen, in2 = u2 < rlen;
        if (!(in0 || in1 || in2)) continue;

        P3 p0 = *reinterpret_cast<const P3*>(Vb + (size_t)ix.a * 3);
        P3 p1 = *reinterpret_cast<const P3*>(Vb + (size_t)ix.b * 3);
        P3 p2 = *reinterpret_cast<const P3*>(Vb + (size_t)ix.c * 3);

        float w0, w1, w2;
        cot_weights(p0, p1, p2, w0, w1, w2);

        if (in0) {
            atomicAdd(&lacc[u0 * 3 + 0], w1 * (p2.x - p0.x) + w2 * (p1.x - p0.x));
            atomicAdd(&lacc[u0 * 3 + 1], w1 * (p2.y - p0.y) + w2 * (p1.y - p0.y));
            atomicAdd(&lacc[u0 * 3 + 2], w1 * (p2.z - p0.z) + w2 * (p1.z - p0.z));
        }
        if (in1) {
            atomicAdd(&lacc[u1 * 3 + 0], w0 * (p2.x - p1.x) + w2 * (p0.x - p1.x));
            atomicAdd(&lacc[u1 * 3 + 1], w0 * (p2.y - p1.y) + w2 * (p0.y - p1.y));
            atomicAdd(&lacc[u1 * 3 + 2], w0 * (p2.z - p1.z) + w2 * (p0.z - p1.z));
        }
        if (in2) {
            atomicAdd(&lacc[u2 * 3 + 0], w0 * (p1.x - p2.x) + w1 * (p0.x - p2.x));
            atomicAdd(&lacc[u2 * 3 + 1], w0 * (p1.y - p2.y) + w1 * (p0.y - p2.y));
            atomicAdd(&lacc[u2 * 3 + 2], w0 * (p1.z - p2.z) + w1 * (p0.z - p2.z));
        }
    }
    __syncthreads();

    float* dst = part + (size_t)s * BN3 + ((size_t)b * N + lo) * 3;
    for (int i = threadIdx.x; i < len3; i += 1024) dst[i] = lacc[i];
}

// Fallback 2 (tiny ws): 9 device-scope atomics into d_out.
__global__ void __launch_bounds__(256) cot_face_add9(
    const float* __restrict__ V, const int* __restrict__ F,
    float* __restrict__ out, int N, int Fc)
{
    int idx = blockIdx.x * blockDim.x + threadIdx.x;
    int total = NBATCH * Fc;
    if (idx >= total) return;

    int b = idx / Fc;
    I3 ix = *reinterpret_cast<const I3*>(F + (size_t)idx * 3);
    int vb = b * N;
    int g0 = vb + ix.a, g1 = vb + ix.b, g2 = vb + ix.c;

    P3 p0 = *reinterpret_cast<const P3*>(V + (size_t)g0 * 3);
    P3 p1 = *reinterpret_cast<const P3*>(V + (size_t)g1 * 3);
    P3 p2 = *reinterpret_cast<const P3*>(V + (size_t)g2 * 3);

    float w0, w1, w2;
    cot_weights(p0, p1, p2, w0, w1, w2);

    atomicAdd(&out[(size_t)g0 * 3 + 0], w1 * (p2.x - p0.x) + w2 * (p1.x - p0.x));
    atomicAdd(&out[(size_t)g0 * 3 + 1], w1 * (p2.y - p0.y) + w2 * (p1.y - p0.y));
    atomicAdd(&out[(size_t)g0 * 3 + 2], w1 * (p2.z - p0.z) + w2 * (p1.z - p0.z));
    atomicAdd(&out[(size_t)g1 * 3 + 0], w0 * (p2.x - p1.x) + w2 * (p0.x - p1.x));
    atomicAdd(&out[(size_t)g1 * 3 + 1], w0 * (p2.y - p1.y) + w2 * (p0.y - p1.y));
    atomicAdd(&out[(size_t)g1 * 3 + 2], w0 * (p2.z - p1.z) + w2 * (p0.z - p1.z));
    atomicAdd(&out[(size_t)g2 * 3 + 0], w0 * (p1.x - p2.x) + w1 * (p0.x - p2.x));
    atomicAdd(&out[(size_t)g2 * 3 + 1], w0 * (p1.y - p2.y) + w1 * (p0.y - p2.y));
    atomicAdd(&out[(size_t)g2 * 3 + 2], w0 * (p1.z - p2.z) + w1 * (p0.z - p2.z));
}

extern "C" void kernel_launch(void* const* d_in, const int* in_sizes, int n_in,
                              void* d_out, int out_size, void* d_ws, size_t ws_size,
                              hipStream_t stream) {
    const float* V = (const float*)d_in[0];
    const int*   F = (const int*)d_in[1];
    float* out = (float*)d_out;

    int BN3 = in_sizes[0];            // B*N*3
    int N   = BN3 / (NBATCH * 3);
    int Fc  = in_sizes[1] / (NBATCH * 3);
    int totalF = NBATCH * Fc;

    size_t cbytes = (size_t)totalF * 9 * sizeof(float);   // 57.6 MB
    size_t pbytes = (size_t)BN3 * sizeof(float);          //  9.6 MB per partial

    // Largest nseg in [1, MAXSEG] whose partials fit next to cbuf.
    int nseg = 0;
    for (int s = MAXSEG; s >= 1; --s)
        if (ws_size >= cbytes + (size_t)s * pbytes) { nseg = s; break; }

    const int dynLds = RANGE_BIG * 3 * sizeof(float);  // 159744 B
    int nr = (N + RANGE_BIG - 1) / RANGE_BIG;

    if (nseg > 0) {
        hipError_t ok = hipFuncSetAttribute(
            reinterpret_cast<const void*>(cot_scatter_big),
            hipFuncAttributeMaxDynamicSharedMemorySize, dynLds);
        if (ok == hipSuccess) {
            float* cbuf = (float*)d_ws;
            float* part = (float*)((char*)d_ws + cbytes);

            int pblocks = (totalF + 255) / 256;
            cot_prep<<<pblocks, 256, 0, stream>>>(V, F, cbuf, N, Fc);

            int sblocks = NBATCH * nr * nseg;
            cot_scatter_big<<<sblocks, 1024, dynLds, stream>>>(F, cbuf, part, N, Fc, BN3, nseg);

            if ((BN3 & 3) == 0) {
                int mblocks = ((BN3 >> 2) + 255) / 256;
                cot_merge4<<<mblocks, 256, 0, stream>>>(part, out, BN3, nseg);
            } else {
                int mblocks = (BN3 + 255) / 256;
                cot_merge1<<<mblocks, 256, 0, stream>>>(part, out, BN3, nseg);
            }
            return;
        }
    }

    // Fallback 1: round-9 fused gather (needs 4 partials = 38.4 MB).
    if (ws_size >= 4 * pbytes &&
        hipFuncSetAttribute(reinterpret_cast<const void*>(cot_gather_big),
                            hipFuncAttributeMaxDynamicSharedMemorySize,
                            dynLds) == hipSuccess) {
        int fseg = 4;
        int gblocks = NBATCH * nr * fseg;
        cot_gather_big<<<gblocks, 1024, dynLds, stream>>>(V, F, (float*)d_ws, N, Fc, BN3, fseg);
        if ((BN3 & 3) == 0) {
            int mblocks = ((BN3 >> 2) + 255) / 256;
            cot_merge4<<<mblocks, 256, 0, stream>>>((const float*)d_ws, out, BN3, fseg);
        } else {
            int mblocks = (BN3 + 255) / 256;
            cot_merge1<<<mblocks, 256, 0, stream>>>((const float*)d_ws, out, BN3, fseg);
        }
        return;
    }

    // Fallback 2: direct device-scope atomics.
    hipMemsetAsync(d_out, 0, (size_t)BN3 * sizeof(float), stream);
    int fblocks = (totalF + 255) / 256;
    cot_face_add9<<<fblocks, 256, 0, stream>>>(V, F, out, N, Fc);
}